// Round 1
// baseline (184.388 us; speedup 1.0000x reference)
//
#include <hip/hip_runtime.h>
#include <hip/hip_bf16.h>

// Problem: VQVAE quantize.
// x: [8, 64, 32, 32] fp32, codebook: [8192, 64] fp32.
// Outputs (concat flat in d_out, fp32):
//   [0,           524288) quant_out [8,64,32,32]
//   [524288]             commitment_loss
//   [524289]             codebook_loss
//   [524290,     532482) indices [8,32,32] as float
//
// N = B*H*W = 8192 points, K = 8192 codes, C = 64.
// argmin_k (x2[n] + e2[k] - 2*dot(x_n, e_k))  -- fp32 to match np reference.

#define N_PTS   8192
#define K_CODES 8192
#define C_DIM   64
#define HWSZ    1024          // H*W
#define QOUT_N  524288        // 8*64*1024

// ---- workspace layout (bytes) ----
#define WS_CBT   0            // float [64][8192]  = 2097152 B
#define WS_E2    2097152      // float [8192]      = 32768 B
#define WS_X2    2129920      // float [8192]      = 32768 B
#define WS_PACK  2162688      // u64   [8192]      = 65536 B
#define WS_LOSS  2228224      // float [1]

// ============================================================
// Kernel A: prep. 8192 threads. Thread t handles codebook row t
// (e2 + transpose into cbT) and point t (x2), inits packed/loss.
// ============================================================
__global__ __launch_bounds__(256)
void vq_prep_kernel(const float* __restrict__ x,
                    const float* __restrict__ cb,
                    float* __restrict__ cbT,
                    float* __restrict__ e2,
                    float* __restrict__ x2,
                    unsigned long long* __restrict__ packed,
                    float* __restrict__ lossAcc)
{
    const int t = blockIdx.x * 256 + threadIdx.x;   // 0..8191

    // codebook row t: e2 + transpose (writes coalesced across lanes)
    float s = 0.0f;
    #pragma unroll
    for (int c4 = 0; c4 < 16; ++c4) {
        float4 q = *(const float4*)(cb + t * C_DIM + c4 * 4);
        s += q.x * q.x + q.y * q.y + q.z * q.z + q.w * q.w;
        cbT[(c4 * 4 + 0) * K_CODES + t] = q.x;
        cbT[(c4 * 4 + 1) * K_CODES + t] = q.y;
        cbT[(c4 * 4 + 2) * K_CODES + t] = q.z;
        cbT[(c4 * 4 + 3) * K_CODES + t] = q.w;
    }
    e2[t] = s;

    // point t: x2 (reads coalesced per-c across lanes)
    const int b  = t >> 10;
    const int hw = t & 1023;
    const float* xb = x + b * (C_DIM * HWSZ) + hw;
    float sx = 0.0f;
    #pragma unroll 8
    for (int c = 0; c < C_DIM; ++c) {
        float v = xb[c * HWSZ];
        sx = fmaf(v, v, sx);
    }
    x2[t] = sx;

    packed[t] = ~0ull;
    if (t == 0) *lossAcc = 0.0f;
}

// ============================================================
// Kernel B: argmin GEMM.
// grid (64 point-tiles, 8 K-splits), 256 threads.
// Block tile: 128 points x 128 codes per chunk, 8 chunks (1024 codes).
// Thread (ty,tx): ty=tid>>4 -> 8 points, tx=tid&15 -> 8 codes.
// ============================================================
#define BM 128
#define BK 128
#define SPLITS 8
#define CHUNKS 8

__global__ __launch_bounds__(256, 2)
void vq_argmin_kernel(const float* __restrict__ x,     // [8][64][1024]
                      const float* __restrict__ cbT,   // [64][8192]
                      const float* __restrict__ e2,    // [8192]
                      const float* __restrict__ x2,    // [8192]
                      unsigned long long* __restrict__ packed)
{
    __shared__ float xs[C_DIM][BM];   // 32 KB  xs[c][m]
    __shared__ float cs[C_DIM][BK];   // 32 KB  cs[c][kk]

    const int tid = threadIdx.x;
    const int tx  = tid & 15;
    const int ty  = tid >> 4;
    const int mt    = blockIdx.x;   // 0..63
    const int split = blockIdx.y;   // 0..7
    const int n0  = mt * BM;
    const int b   = mt >> 3;
    const int hw0 = (mt & 7) * BM;
    const float* xbase = x + b * (C_DIM * HWSZ) + hw0;

    // stage xs: 2048 float4s, fully coalesced, contiguous LDS b128 writes
    #pragma unroll
    for (int i = 0; i < 8; ++i) {
        int f  = tid + i * 256;        // 0..2047
        int c  = f >> 5;
        int m4 = (f & 31) << 2;
        *(float4*)&xs[c][m4] = *(const float4*)(xbase + c * HWSZ + m4);
    }

    float x2r[8];
    #pragma unroll
    for (int mi = 0; mi < 8; ++mi) x2r[mi] = x2[n0 + ty * 8 + mi];

    unsigned long long best[8];
    #pragma unroll
    for (int mi = 0; mi < 8; ++mi) best[mi] = ~0ull;

    for (int ch = 0; ch < CHUNKS; ++ch) {
        const int k0 = split * (CHUNKS * BK) + ch * BK;

        // stage cs from transposed codebook: same clean pattern as xs
        #pragma unroll
        for (int i = 0; i < 8; ++i) {
            int f  = tid + i * 256;
            int c  = f >> 5;
            int k4 = (f & 31) << 2;
            *(float4*)&cs[c][k4] = *(const float4*)(cbT + c * K_CODES + k0 + k4);
        }
        __syncthreads();

        float acc[8][8];
        #pragma unroll
        for (int mi = 0; mi < 8; ++mi)
            #pragma unroll
            for (int ki = 0; ki < 8; ++ki) acc[mi][ki] = 0.0f;

        #pragma unroll 4
        for (int c = 0; c < C_DIM; ++c) {
            float4 xq0 = *(const float4*)&xs[c][ty * 8];
            float4 xq1 = *(const float4*)&xs[c][ty * 8 + 4];
            float4 cq0 = *(const float4*)&cs[c][tx * 8];
            float4 cq1 = *(const float4*)&cs[c][tx * 8 + 4];
            float xv[8] = {xq0.x, xq0.y, xq0.z, xq0.w, xq1.x, xq1.y, xq1.z, xq1.w};
            float cv[8] = {cq0.x, cq0.y, cq0.z, cq0.w, cq1.x, cq1.y, cq1.z, cq1.w};
            #pragma unroll
            for (int mi = 0; mi < 8; ++mi)
                #pragma unroll
                for (int ki = 0; ki < 8; ++ki)
                    acc[mi][ki] = fmaf(xv[mi], cv[ki], acc[mi][ki]);
        }

        // epilogue: distances + packed argmin update
        float e2v[8];
        *(float4*)&e2v[0] = *(const float4*)(e2 + k0 + tx * 8);
        *(float4*)&e2v[4] = *(const float4*)(e2 + k0 + tx * 8 + 4);
        #pragma unroll
        for (int mi = 0; mi < 8; ++mi) {
            #pragma unroll
            for (int ki = 0; ki < 8; ++ki) {
                float d = (x2r[mi] + e2v[ki]) - 2.0f * acc[mi][ki];
                unsigned int u = __float_as_uint(d);
                u = (u & 0x80000000u) ? ~u : (u | 0x80000000u);
                unsigned long long p =
                    ((unsigned long long)u << 32) | (unsigned)(k0 + tx * 8 + ki);
                best[mi] = (p < best[mi]) ? p : best[mi];
            }
        }
        __syncthreads();   // before cs/xs reuse next chunk / scratch reuse
    }

    // block reduce across tx (16 candidates per point), then one atomic/pt
    unsigned long long* sred = (unsigned long long*)&xs[0][0]; // 128*17*8 B
    #pragma unroll
    for (int mi = 0; mi < 8; ++mi)
        sred[(ty * 8 + mi) * 17 + tx] = best[mi];
    __syncthreads();
    if (tid < BM) {
        unsigned long long v = sred[tid * 17];
        #pragma unroll
        for (int t = 1; t < 16; ++t) {
            unsigned long long w = sred[tid * 17 + t];
            v = (w < v) ? w : v;
        }
        atomicMin(packed + n0 + tid, v);
    }
}

// ============================================================
// Kernel C: gather + quant_out + indices + loss partials.
// ============================================================
__global__ __launch_bounds__(256)
void vq_gather_kernel(const float* __restrict__ x,
                      const float* __restrict__ cb,
                      const unsigned long long* __restrict__ packed,
                      float* __restrict__ out,
                      float* __restrict__ lossAcc)
{
    const int n = blockIdx.x * 256 + threadIdx.x;   // 0..8191
    const unsigned idx = (unsigned)(packed[n] & 0xFFFFFFFFull);
    const int b  = n >> 10;
    const int hw = n & 1023;
    const float* xb = x   + b * (C_DIM * HWSZ) + hw;
    float*       ob = out + b * (C_DIM * HWSZ) + hw;

    float s = 0.0f;
    #pragma unroll
    for (int c4 = 0; c4 < 16; ++c4) {
        float4 q = *(const float4*)(cb + (size_t)idx * C_DIM + c4 * 4);
        float qa[4] = {q.x, q.y, q.z, q.w};
        #pragma unroll
        for (int j = 0; j < 4; ++j) {
            int c = c4 * 4 + j;
            float xv = xb[c * HWSZ];
            float d  = qa[j] - xv;         // quant - x (rounded, as reference)
            s = fmaf(d, d, s);
            ob[c * HWSZ] = xv + d;         // straight-through: x + (q - x)
        }
    }

    // indices as float
    out[QOUT_N + 2 + n] = (float)idx;

    // wave reduce, one atomic per wave
    #pragma unroll
    for (int off = 32; off > 0; off >>= 1) s += __shfl_down(s, off, 64);
    if ((threadIdx.x & 63) == 0) atomicAdd(lossAcc, s);
}

// ============================================================
// Kernel D: finalize the two loss scalars.
// ============================================================
__global__ void vq_final_kernel(const float* __restrict__ lossAcc,
                                float* __restrict__ out)
{
    float m = *lossAcc * (1.0f / (float)QOUT_N);
    out[QOUT_N]     = m;   // commitment_loss
    out[QOUT_N + 1] = m;   // codebook_loss (same value)
}

extern "C" void kernel_launch(void* const* d_in, const int* in_sizes, int n_in,
                              void* d_out, int out_size, void* d_ws, size_t ws_size,
                              hipStream_t stream)
{
    const float* x  = (const float*)d_in[0];   // [8,64,32,32]
    const float* cb = (const float*)d_in[1];   // [8192,64]
    float* out = (float*)d_out;
    char*  ws  = (char*)d_ws;

    float* cbT = (float*)(ws + WS_CBT);
    float* e2  = (float*)(ws + WS_E2);
    float* x2  = (float*)(ws + WS_X2);
    unsigned long long* packed = (unsigned long long*)(ws + WS_PACK);
    float* lossAcc = (float*)(ws + WS_LOSS);

    vq_prep_kernel<<<N_PTS / 256, 256, 0, stream>>>(x, cb, cbT, e2, x2, packed, lossAcc);
    vq_argmin_kernel<<<dim3(N_PTS / BM, SPLITS), 256, 0, stream>>>(x, cbT, e2, x2, packed);
    vq_gather_kernel<<<N_PTS / 256, 256, 0, stream>>>(x, cb, packed, out, lossAcc);
    vq_final_kernel<<<1, 1, 0, stream>>>(lossAcc, out);
}